// Round 4
// baseline (1058.115 us; speedup 1.0000x reference)
//
#include <hip/hip_runtime.h>

#define N_NODES 100000
#define N_EDGES 1600000
#define IN_F 256
#define OUT_F 128
#define SCAN_NB ((N_NODES + 255) / 256)   // 391 (also = number of coarse buckets)
#define BUCKET_CAP 5120                   // avg 4092, +16 sigma headroom

// ---------------- kernel 1: masked weight  wm = (mask>0.5)?w:0 ----------------
__global__ void mask_w_kernel(const float* __restrict__ weight,
                              const float* __restrict__ mask_real,
                              float* __restrict__ wm) {
    int i = blockIdx.x * blockDim.x + threadIdx.x;
    if (i < IN_F * OUT_F)
        wm[i] = (mask_real[i] > 0.5f) ? weight[i] : 0.0f;
}

// ---------------- kernel 2: fused degree count + coarse bucket scatter ----------------
// bucket b = dst>>8 (256 nodes per bucket). Sequential cursor allocation per
// bucket concentrates writes on ~391 hot cachelines -> L2 write combining.
__global__ void deg_fill_kernel(const int* __restrict__ src,
                                const int* __restrict__ dst,
                                const float* __restrict__ ew,
                                unsigned* __restrict__ outdeg,
                                unsigned* __restrict__ indeg,
                                unsigned* __restrict__ bcnt,
                                uint2* __restrict__ tmp) {
    int e = blockIdx.x * blockDim.x + threadIdx.x;
    if (e < N_EDGES) {
        int s = src[e];
        int d = dst[e];
        atomicAdd(&outdeg[s], 1u);
        atomicAdd(&indeg[d], 1u);
        unsigned b = (unsigned)d >> 8;
        unsigned j = atomicAdd(&bcnt[b], 1u);
        if (j < BUCKET_CAP) {
            uint2 m;
            m.x = (unsigned)s | (((unsigned)d & 255u) << 17);
            m.y = __float_as_uint(ew[e]);
            tmp[(size_t)b * BUCKET_CAP + j] = m;
        }
    }
}

// ---------------- hierarchical exclusive scan of indeg -> offsets ----------------
__global__ __launch_bounds__(256) void scan_reduce(const unsigned* __restrict__ indeg,
                                                   unsigned* __restrict__ bsum) {
    __shared__ unsigned red[256];
    int t = threadIdx.x;
    int i = blockIdx.x * 256 + t;
    red[t] = (i < N_NODES) ? indeg[i] : 0u;
    __syncthreads();
#pragma unroll
    for (int d = 128; d > 0; d >>= 1) {
        if (t < d) red[t] += red[t + d];
        __syncthreads();
    }
    if (t == 0) bsum[blockIdx.x] = red[0];
}

__global__ __launch_bounds__(512) void scan_spine(const unsigned* __restrict__ bsum,
                                                  unsigned* __restrict__ bpref,
                                                  unsigned* __restrict__ offsets) {
    __shared__ unsigned part[512];
    int t = threadIdx.x;
    unsigned v = (t < SCAN_NB) ? bsum[t] : 0u;
    part[t] = v;
    __syncthreads();
#pragma unroll
    for (int d = 1; d < 512; d <<= 1) {
        unsigned x = (t >= d) ? part[t - d] : 0u;
        __syncthreads();
        part[t] += x;
        __syncthreads();
    }
    if (t < SCAN_NB) bpref[t] = part[t] - v;    // exclusive
    if (t == 511) offsets[N_NODES] = part[511]; // grand total
}

__global__ __launch_bounds__(256) void scan_apply(const unsigned* __restrict__ indeg,
                                                  const unsigned* __restrict__ bpref,
                                                  unsigned* __restrict__ offsets) {
    __shared__ unsigned part[256];
    int t = threadIdx.x;
    int i = blockIdx.x * 256 + t;
    unsigned v = (i < N_NODES) ? indeg[i] : 0u;
    part[t] = v;
    __syncthreads();
#pragma unroll
    for (int d = 1; d < 256; d <<= 1) {
        unsigned x = (t >= d) ? part[t - d] : 0u;
        __syncthreads();
        part[t] += x;
        __syncthreads();
    }
    if (i < N_NODES) offsets[i] = bpref[blockIdx.x] + part[t] - v;
}

// ---------------- kernel 4: bucket -> final CSR position (LDS cursors) ----------------
// One block per coarse bucket; final positions span a contiguous ~32 KB window
// of smeta -> L2-resident scatter, full-line write-back, zero global atomics.
__global__ __launch_bounds__(256) void fillB_kernel(const uint2* __restrict__ tmp,
                                                    const unsigned* __restrict__ bcnt,
                                                    const unsigned* __restrict__ offsets,
                                                    uint2* __restrict__ smeta) {
    __shared__ unsigned cur[256];
    int b = blockIdx.x;
    int t = threadIdx.x;
    int node = b * 256 + t;
    cur[t] = (node < N_NODES) ? offsets[node] : 0u;
    __syncthreads();
    int cnt = (int)min(bcnt[b], (unsigned)BUCKET_CAP);
    const uint2* tb = tmp + (size_t)b * BUCKET_CAP;
    for (int i = t; i < cnt; i += 256) {
        uint2 m = tb[i];
        unsigned dl = m.x >> 17;
        unsigned pos = atomicAdd(&cur[dl], 1u);
        smeta[pos] = make_uint2(m.x & 0x1FFFFu, m.y);
    }
}

// ---------------- kernel 5: fp32 GEMM  h = (feat * outscale) @ wm, bf16 output ----------------
#define MT 32
#define KT 64

#define MMA_ROW(R, A)                                   \
    acc[R][0] = fmaf((A).x, b0.x, acc[R][0]);           \
    acc[R][0] = fmaf((A).y, b1.x, acc[R][0]);           \
    acc[R][0] = fmaf((A).z, b2.x, acc[R][0]);           \
    acc[R][0] = fmaf((A).w, b3.x, acc[R][0]);           \
    acc[R][1] = fmaf((A).x, b0.y, acc[R][1]);           \
    acc[R][1] = fmaf((A).y, b1.y, acc[R][1]);           \
    acc[R][1] = fmaf((A).z, b2.y, acc[R][1]);           \
    acc[R][1] = fmaf((A).w, b3.y, acc[R][1]);           \
    acc[R][2] = fmaf((A).x, b0.z, acc[R][2]);           \
    acc[R][2] = fmaf((A).y, b1.z, acc[R][2]);           \
    acc[R][2] = fmaf((A).z, b2.z, acc[R][2]);           \
    acc[R][2] = fmaf((A).w, b3.z, acc[R][2]);           \
    acc[R][3] = fmaf((A).x, b0.w, acc[R][3]);           \
    acc[R][3] = fmaf((A).y, b1.w, acc[R][3]);           \
    acc[R][3] = fmaf((A).z, b2.w, acc[R][3]);           \
    acc[R][3] = fmaf((A).w, b3.w, acc[R][3]);

__device__ __forceinline__ unsigned bf16_rne(float f) {
    unsigned u = __float_as_uint(f);
    return (u + 0x7fffu + ((u >> 16) & 1u)) >> 16;
}

__global__ __launch_bounds__(256) void gemm_kernel(const float* __restrict__ feat,
                                                   const float* __restrict__ wm,
                                                   const unsigned* __restrict__ outdeg,
                                                   unsigned* __restrict__ hrows) {
    __shared__ float sA[MT][KT];      // 8 KB
    __shared__ float sB[KT][OUT_F];   // 32 KB
    int t = threadIdx.x;
    int row0 = blockIdx.x * MT;
    int fg = (t & 31) * 4;
    int rg = (t >> 5) * 4;
    float acc[4][4] = {};

    for (int k0 = 0; k0 < IN_F; k0 += KT) {
        {
            int lr = t >> 4;
            int lc = (t & 15) * 4;
            float4 v0 = *(const float4*)&feat[(size_t)(row0 + lr) * IN_F + k0 + lc];
            float4 v1 = *(const float4*)&feat[(size_t)(row0 + lr + 16) * IN_F + k0 + lc];
            *(float4*)&sA[lr][lc] = v0;
            *(float4*)&sA[lr + 16][lc] = v1;
        }
        {
            int bk = t >> 5;
            int bf = (t & 31) * 4;
#pragma unroll
            for (int kk = 0; kk < KT; kk += 8) {
                *(float4*)&sB[bk + kk][bf] =
                    *(const float4*)&wm[(size_t)(k0 + bk + kk) * OUT_F + bf];
            }
        }
        __syncthreads();
#pragma unroll
        for (int k = 0; k < KT; k += 4) {
            float4 a0 = *(const float4*)&sA[rg + 0][k];
            float4 a1 = *(const float4*)&sA[rg + 1][k];
            float4 a2 = *(const float4*)&sA[rg + 2][k];
            float4 a3 = *(const float4*)&sA[rg + 3][k];
            float4 b0 = *(const float4*)&sB[k + 0][fg];
            float4 b1 = *(const float4*)&sB[k + 1][fg];
            float4 b2 = *(const float4*)&sB[k + 2][fg];
            float4 b3 = *(const float4*)&sB[k + 3][fg];
            MMA_ROW(0, a0)
            MMA_ROW(1, a1)
            MMA_ROW(2, a2)
            MMA_ROW(3, a3)
        }
        __syncthreads();
    }
#pragma unroll
    for (int r = 0; r < 4; r++) {
        unsigned dg = outdeg[row0 + rg + r];
        float s = rsqrtf(fmaxf((float)dg, 1.0f));
        unsigned p0 = bf16_rne(acc[r][0] * s) | (bf16_rne(acc[r][1] * s) << 16);
        unsigned p1 = bf16_rne(acc[r][2] * s) | (bf16_rne(acc[r][3] * s) << 16);
        uint2 pk = make_uint2(p0, p1);
        *(uint2*)&hrows[(size_t)(row0 + rg + r) * (OUT_F / 2) + (fg >> 1)] = pk;
    }
}

// ---------------- kernel 6: CSR gather-sum, one wave per dst node ----------------
__global__ __launch_bounds__(256) void gather_kernel(const uint2* __restrict__ smeta,
                                                     const unsigned* __restrict__ offsets,
                                                     const unsigned* __restrict__ hrows,
                                                     const float* __restrict__ bias,
                                                     float* __restrict__ out) {
    int lane = threadIdx.x & 63;
    int n = blockIdx.x * 4 + (threadIdx.x >> 6);
    unsigned beg = offsets[n], end = offsets[n + 1];
    int deg = (int)(end - beg);
    float acc0 = 0.0f, acc1 = 0.0f;
    for (int base = 0; base < deg; base += 64) {
        int c = min(64, deg - base);
        unsigned sv = 0;
        float wv = 0.0f;
        if (lane < c) {
            uint2 m = smeta[beg + base + lane];
            sv = m.x;
            wv = __uint_as_float(m.y);
        }
#pragma unroll 4
        for (int i = 0; i < c; i++) {
            unsigned s = __shfl(sv, i);
            float w = __shfl(wv, i);
            unsigned hv = hrows[(size_t)s * (OUT_F / 2) + lane];
            float lo = __uint_as_float(hv << 16);
            float hi = __uint_as_float(hv & 0xffff0000u);
            acc0 = fmaf(lo, w, acc0);
            acc1 = fmaf(hi, w, acc1);
        }
    }
    float s = rsqrtf(fmaxf((float)deg, 1.0f));
    float2 b = *(const float2*)&bias[2 * lane];
    float2 o = make_float2(acc0 * s + b.x, acc1 * s + b.y);
    *(float2*)&out[(size_t)n * OUT_F + 2 * lane] = o;
}

extern "C" void kernel_launch(void* const* d_in, const int* in_sizes, int n_in,
                              void* d_out, int out_size, void* d_ws, size_t ws_size,
                              hipStream_t stream) {
    const float* feat      = (const float*)d_in[0];
    const int*   src       = (const int*)d_in[1];
    const int*   dst       = (const int*)d_in[2];
    const float* ew        = (const float*)d_in[3];
    const float* weight    = (const float*)d_in[4];
    const float* bias      = (const float*)d_in[5];
    const float* mask_real = (const float*)d_in[6];
    float* out = (float*)d_out;

    char* ws = (char*)d_ws;
    size_t o = 0;
    auto take = [&](size_t bytes) {
        char* p = ws + o;
        o = (o + bytes + 255) & ~(size_t)255;
        return p;
    };
    float*    wm     = (float*)take((size_t)IN_F * OUT_F * 4);
    unsigned* outdeg = (unsigned*)take((size_t)N_NODES * 4);
    unsigned* indeg  = (unsigned*)take((size_t)N_NODES * 4);
    unsigned* offs   = (unsigned*)take((size_t)(N_NODES + 1) * 4);
    unsigned* bcnt   = (unsigned*)take((size_t)SCAN_NB * 4);
    uint2*    tmp    = (uint2*)take((size_t)SCAN_NB * BUCKET_CAP * 8);
    uint2*    smeta  = (uint2*)take((size_t)N_EDGES * 8);
    unsigned* bsum   = (unsigned*)take((size_t)SCAN_NB * 4);
    unsigned* bpref  = (unsigned*)take((size_t)SCAN_NB * 4);
    unsigned* hrows  = (unsigned*)take((size_t)N_NODES * (OUT_F / 2) * 4);

    hipMemsetAsync(outdeg, 0, (size_t)N_NODES * 4, stream);
    hipMemsetAsync(indeg, 0, (size_t)N_NODES * 4, stream);
    hipMemsetAsync(bcnt, 0, (size_t)SCAN_NB * 4, stream);

    mask_w_kernel<<<(IN_F * OUT_F + 255) / 256, 256, 0, stream>>>(weight, mask_real, wm);
    deg_fill_kernel<<<(N_EDGES + 255) / 256, 256, 0, stream>>>(src, dst, ew, outdeg, indeg,
                                                               bcnt, tmp);
    scan_reduce<<<SCAN_NB, 256, 0, stream>>>(indeg, bsum);
    scan_spine<<<1, 512, 0, stream>>>(bsum, bpref, offs);
    scan_apply<<<SCAN_NB, 256, 0, stream>>>(indeg, bpref, offs);
    gemm_kernel<<<N_NODES / MT, 256, 0, stream>>>(feat, wm, outdeg, hrows);
    fillB_kernel<<<SCAN_NB, 256, 0, stream>>>(tmp, bcnt, offs, smeta);
    gather_kernel<<<N_NODES / 4, 256, 0, stream>>>(smeta, offs, hrows, bias, out);
}

// Round 5
// 485.907 us; speedup vs baseline: 2.1776x; 2.1776x over previous
//
#include <hip/hip_runtime.h>

#define N_NODES 100000
#define N_EDGES 1600000
#define IN_F 256
#define OUT_F 128
#define NBUCK 391          // coarse buckets of 256 dst-nodes
#define NPART 256          // edge partitions
#define CHUNK (N_EDGES / NPART)   // 6250
#define BCAP 5632          // max edges staged per bucket in fillB (avg 4092, +24 sigma)

// ---------------- masked weight ----------------
__global__ void mask_w_kernel(const float* __restrict__ weight,
                              const float* __restrict__ mask_real,
                              float* __restrict__ wm) {
    int i = blockIdx.x * blockDim.x + threadIdx.x;
    if (i < IN_F * OUT_F)
        wm[i] = (mask_real[i] > 0.5f) ? weight[i] : 0.0f;
}

// ---------------- out-degree (for GEMM row scaling) ----------------
__global__ void outdeg_kernel(const int* __restrict__ src, unsigned* __restrict__ outdeg) {
    int e = blockIdx.x * blockDim.x + threadIdx.x;
    if (e < N_EDGES) atomicAdd(&outdeg[src[e]], 1u);
}

// ---------------- pass 1: per-partition bucket histogram (LDS) ----------------
__global__ __launch_bounds__(256) void hist_kernel(const int* __restrict__ dst,
                                                   unsigned* __restrict__ hist) {
    __shared__ unsigned h[NBUCK];
    int p = blockIdx.x, t = threadIdx.x;
    for (int b = t; b < NBUCK; b += 256) h[b] = 0u;
    __syncthreads();
    int base = p * CHUNK;
    for (int i = t; i < CHUNK; i += 256)
        atomicAdd(&h[(unsigned)dst[base + i] >> 8], 1u);
    __syncthreads();
    for (int b = t; b < NBUCK; b += 256)
        hist[(size_t)p * NBUCK + b] = h[b];   // partition-major: contiguous write per block
}

// ---------------- scan of hist in (bucket, partition) order ----------------
// element (b,p) lives at hist[p*NBUCK + b]; scanned output is bucket-major.
__global__ __launch_bounds__(256) void scan_reduce_hist(const unsigned* __restrict__ hist,
                                                        unsigned* __restrict__ bsum) {
    __shared__ unsigned red[256];
    int b = blockIdx.x, t = threadIdx.x;
    red[t] = hist[(size_t)t * NBUCK + b];
    __syncthreads();
#pragma unroll
    for (int d = 128; d > 0; d >>= 1) {
        if (t < d) red[t] += red[t + d];
        __syncthreads();
    }
    if (t == 0) bsum[b] = red[0];
}

__global__ __launch_bounds__(512) void scan_spine(const unsigned* __restrict__ bsum,
                                                  unsigned* __restrict__ bpref) {
    __shared__ unsigned part[512];
    int t = threadIdx.x;
    unsigned v = (t < NBUCK) ? bsum[t] : 0u;
    part[t] = v;
    __syncthreads();
#pragma unroll
    for (int d = 1; d < 512; d <<= 1) {
        unsigned x = (t >= d) ? part[t - d] : 0u;
        __syncthreads();
        part[t] += x;
        __syncthreads();
    }
    if (t < NBUCK) bpref[t] = part[t] - v;   // exclusive bucket base
}

__global__ __launch_bounds__(256) void scan_apply_hist(const unsigned* __restrict__ hist,
                                                       const unsigned* __restrict__ bpref,
                                                       unsigned* __restrict__ scanned) {
    __shared__ unsigned part[256];
    int b = blockIdx.x, t = threadIdx.x;
    unsigned v = hist[(size_t)t * NBUCK + b];
    part[t] = v;
    __syncthreads();
#pragma unroll
    for (int d = 1; d < 256; d <<= 1) {
        unsigned x = (t >= d) ? part[t - d] : 0u;
        __syncthreads();
        part[t] += x;
        __syncthreads();
    }
    scanned[(size_t)b * 256 + t] = bpref[b] + part[t] - v;   // base for (partition t, bucket b)
}

// ---------------- pass 2: scatter edges to bucket-major tmp (private ranges) ----------------
__global__ __launch_bounds__(256) void scatter_kernel(const int* __restrict__ src,
                                                      const int* __restrict__ dst,
                                                      const float* __restrict__ ew,
                                                      const unsigned* __restrict__ scanned,
                                                      uint2* __restrict__ tmp) {
    __shared__ unsigned cur[NBUCK];
    int p = blockIdx.x, t = threadIdx.x;
    for (int b = t; b < NBUCK; b += 256) cur[b] = scanned[(size_t)b * 256 + p];
    __syncthreads();
    int base = p * CHUNK;
    for (int i = t; i < CHUNK; i += 256) {
        int e = base + i;
        int s = src[e];
        int d = dst[e];
        unsigned pos = atomicAdd(&cur[(unsigned)d >> 8], 1u);
        tmp[pos] = make_uint2((unsigned)s | (((unsigned)d & 255u) << 17),
                              __float_as_uint(ew[e]));
    }
}

// ---------------- fillB: bucket -> per-node CSR + offsets (all in LDS, one XCD window) ----------------
__global__ __launch_bounds__(256) void fillB_kernel(const uint2* __restrict__ tmp,
                                                    const unsigned* __restrict__ scanned,
                                                    unsigned* __restrict__ offsets,
                                                    uint2* __restrict__ smeta) {
    __shared__ uint2 ebuf[BCAP];        // 44 KB
    __shared__ unsigned hcnt[256];
    __shared__ unsigned pref[256];
    int b = blockIdx.x, t = threadIdx.x;
    unsigned base = scanned[(size_t)b * 256];
    unsigned next = (b == NBUCK - 1) ? (unsigned)N_EDGES : scanned[(size_t)(b + 1) * 256];
    int cnt = (int)(next - base);
    if (cnt > BCAP) cnt = BCAP;         // statistically impossible; guard anyway
    hcnt[t] = 0u;
    for (int i = t; i < cnt; i += 256) ebuf[i] = tmp[base + i];
    __syncthreads();
    for (int i = t; i < cnt; i += 256) atomicAdd(&hcnt[ebuf[i].x >> 17], 1u);
    __syncthreads();
    unsigned v = hcnt[t];
    pref[t] = v;
    __syncthreads();
#pragma unroll
    for (int d = 1; d < 256; d <<= 1) {
        unsigned x = (t >= d) ? pref[t - d] : 0u;
        __syncthreads();
        pref[t] += x;
        __syncthreads();
    }
    unsigned excl = pref[t] - v;        // exclusive node prefix within bucket
    int node = b * 256 + t;
    if (node <= N_NODES) offsets[node] = base + excl;
    hcnt[t] = base + excl;              // cursor
    __syncthreads();
    for (int i = t; i < cnt; i += 256) {
        uint2 m = ebuf[i];
        unsigned pos = atomicAdd(&hcnt[m.x >> 17], 1u);
        smeta[pos] = make_uint2(m.x & 0x1FFFFu, m.y);
    }
}

// ---------------- fp32 GEMM  h = (feat * outscale) @ wm, bf16 output ----------------
#define MT 32
#define KT 64

#define MMA_ROW(R, A)                                   \
    acc[R][0] = fmaf((A).x, b0.x, acc[R][0]);           \
    acc[R][0] = fmaf((A).y, b1.x, acc[R][0]);           \
    acc[R][0] = fmaf((A).z, b2.x, acc[R][0]);           \
    acc[R][0] = fmaf((A).w, b3.x, acc[R][0]);           \
    acc[R][1] = fmaf((A).x, b0.y, acc[R][1]);           \
    acc[R][1] = fmaf((A).y, b1.y, acc[R][1]);           \
    acc[R][1] = fmaf((A).z, b2.y, acc[R][1]);           \
    acc[R][1] = fmaf((A).w, b3.y, acc[R][1]);           \
    acc[R][2] = fmaf((A).x, b0.z, acc[R][2]);           \
    acc[R][2] = fmaf((A).y, b1.z, acc[R][2]);           \
    acc[R][2] = fmaf((A).z, b2.z, acc[R][2]);           \
    acc[R][2] = fmaf((A).w, b3.z, acc[R][2]);           \
    acc[R][3] = fmaf((A).x, b0.w, acc[R][3]);           \
    acc[R][3] = fmaf((A).y, b1.w, acc[R][3]);           \
    acc[R][3] = fmaf((A).z, b2.w, acc[R][3]);           \
    acc[R][3] = fmaf((A).w, b3.w, acc[R][3]);

__device__ __forceinline__ unsigned bf16_rne(float f) {
    unsigned u = __float_as_uint(f);
    return (u + 0x7fffu + ((u >> 16) & 1u)) >> 16;
}

__global__ __launch_bounds__(256) void gemm_kernel(const float* __restrict__ feat,
                                                   const float* __restrict__ wm,
                                                   const unsigned* __restrict__ outdeg,
                                                   unsigned* __restrict__ hrows) {
    __shared__ float sA[MT][KT];      // 8 KB
    __shared__ float sB[KT][OUT_F];   // 32 KB
    int t = threadIdx.x;
    int row0 = blockIdx.x * MT;
    int fg = (t & 31) * 4;
    int rg = (t >> 5) * 4;
    float acc[4][4] = {};

    for (int k0 = 0; k0 < IN_F; k0 += KT) {
        {
            int lr = t >> 4;
            int lc = (t & 15) * 4;
            float4 v0 = *(const float4*)&feat[(size_t)(row0 + lr) * IN_F + k0 + lc];
            float4 v1 = *(const float4*)&feat[(size_t)(row0 + lr + 16) * IN_F + k0 + lc];
            *(float4*)&sA[lr][lc] = v0;
            *(float4*)&sA[lr + 16][lc] = v1;
        }
        {
            int bk = t >> 5;
            int bf = (t & 31) * 4;
#pragma unroll
            for (int kk = 0; kk < KT; kk += 8) {
                *(float4*)&sB[bk + kk][bf] =
                    *(const float4*)&wm[(size_t)(k0 + bk + kk) * OUT_F + bf];
            }
        }
        __syncthreads();
#pragma unroll
        for (int k = 0; k < KT; k += 4) {
            float4 a0 = *(const float4*)&sA[rg + 0][k];
            float4 a1 = *(const float4*)&sA[rg + 1][k];
            float4 a2 = *(const float4*)&sA[rg + 2][k];
            float4 a3 = *(const float4*)&sA[rg + 3][k];
            float4 b0 = *(const float4*)&sB[k + 0][fg];
            float4 b1 = *(const float4*)&sB[k + 1][fg];
            float4 b2 = *(const float4*)&sB[k + 2][fg];
            float4 b3 = *(const float4*)&sB[k + 3][fg];
            MMA_ROW(0, a0)
            MMA_ROW(1, a1)
            MMA_ROW(2, a2)
            MMA_ROW(3, a3)
        }
        __syncthreads();
    }
#pragma unroll
    for (int r = 0; r < 4; r++) {
        unsigned dg = outdeg[row0 + rg + r];
        float s = rsqrtf(fmaxf((float)dg, 1.0f));
        unsigned p0 = bf16_rne(acc[r][0] * s) | (bf16_rne(acc[r][1] * s) << 16);
        unsigned p1 = bf16_rne(acc[r][2] * s) | (bf16_rne(acc[r][3] * s) << 16);
        uint2 pk = make_uint2(p0, p1);
        *(uint2*)&hrows[(size_t)(row0 + rg + r) * (OUT_F / 2) + (fg >> 1)] = pk;
    }
}

// ---------------- gather: one wave per dst node ----------------
__global__ __launch_bounds__(256) void gather_kernel(const uint2* __restrict__ smeta,
                                                     const unsigned* __restrict__ offsets,
                                                     const unsigned* __restrict__ hrows,
                                                     const float* __restrict__ bias,
                                                     float* __restrict__ out) {
    int lane = threadIdx.x & 63;
    int n = blockIdx.x * 4 + (threadIdx.x >> 6);
    unsigned beg = offsets[n], end = offsets[n + 1];
    int deg = (int)(end - beg);
    float acc0 = 0.0f, acc1 = 0.0f;
    for (int base = 0; base < deg; base += 64) {
        int c = min(64, deg - base);
        unsigned sv = 0;
        float wv = 0.0f;
        if (lane < c) {
            uint2 m = smeta[beg + base + lane];
            sv = m.x;
            wv = __uint_as_float(m.y);
        }
#pragma unroll 4
        for (int i = 0; i < c; i++) {
            unsigned s = __shfl(sv, i);
            float w = __shfl(wv, i);
            unsigned hv = hrows[(size_t)s * (OUT_F / 2) + lane];
            float lo = __uint_as_float(hv << 16);
            float hi = __uint_as_float(hv & 0xffff0000u);
            acc0 = fmaf(lo, w, acc0);
            acc1 = fmaf(hi, w, acc1);
        }
    }
    float s = rsqrtf(fmaxf((float)deg, 1.0f));
    float2 b = *(const float2*)&bias[2 * lane];
    float2 o = make_float2(acc0 * s + b.x, acc1 * s + b.y);
    *(float2*)&out[(size_t)n * OUT_F + 2 * lane] = o;
}

extern "C" void kernel_launch(void* const* d_in, const int* in_sizes, int n_in,
                              void* d_out, int out_size, void* d_ws, size_t ws_size,
                              hipStream_t stream) {
    const float* feat      = (const float*)d_in[0];
    const int*   src       = (const int*)d_in[1];
    const int*   dst       = (const int*)d_in[2];
    const float* ew        = (const float*)d_in[3];
    const float* weight    = (const float*)d_in[4];
    const float* bias      = (const float*)d_in[5];
    const float* mask_real = (const float*)d_in[6];
    float* out = (float*)d_out;

    char* ws = (char*)d_ws;
    size_t o = 0;
    auto take = [&](size_t bytes) {
        char* p = ws + o;
        o = (o + bytes + 255) & ~(size_t)255;
        return p;
    };
    float*    wm      = (float*)take((size_t)IN_F * OUT_F * 4);
    unsigned* outdeg  = (unsigned*)take((size_t)N_NODES * 4);
    unsigned* offs    = (unsigned*)take((size_t)(N_NODES + 1) * 4);
    unsigned* hist    = (unsigned*)take((size_t)NPART * NBUCK * 4);
    unsigned* scanned = (unsigned*)take((size_t)NBUCK * 256 * 4);
    unsigned* bsum    = (unsigned*)take((size_t)NBUCK * 4);
    unsigned* bpref   = (unsigned*)take((size_t)NBUCK * 4);
    uint2*    tmp     = (uint2*)take((size_t)N_EDGES * 8);
    uint2*    smeta   = (uint2*)take((size_t)N_EDGES * 8);
    unsigned* hrows   = (unsigned*)take((size_t)N_NODES * (OUT_F / 2) * 4);

    hipMemsetAsync(outdeg, 0, (size_t)N_NODES * 4, stream);

    mask_w_kernel<<<(IN_F * OUT_F + 255) / 256, 256, 0, stream>>>(weight, mask_real, wm);
    outdeg_kernel<<<(N_EDGES + 255) / 256, 256, 0, stream>>>(src, outdeg);
    hist_kernel<<<NPART, 256, 0, stream>>>(dst, hist);
    scan_reduce_hist<<<NBUCK, 256, 0, stream>>>(hist, bsum);
    scan_spine<<<1, 512, 0, stream>>>(bsum, bpref);
    scan_apply_hist<<<NBUCK, 256, 0, stream>>>(hist, bpref, scanned);
    scatter_kernel<<<NPART, 256, 0, stream>>>(src, dst, ew, scanned, tmp);
    gemm_kernel<<<N_NODES / MT, 256, 0, stream>>>(feat, wm, outdeg, hrows);
    fillB_kernel<<<NBUCK, 256, 0, stream>>>(tmp, scanned, offs, smeta);
    gather_kernel<<<N_NODES / 4, 256, 0, stream>>>(smeta, offs, hrows, bias, out);
}

// Round 6
// 433.670 us; speedup vs baseline: 2.4399x; 1.1205x over previous
//
#include <hip/hip_runtime.h>

#define N_NODES 100000
#define N_EDGES 1600000
#define IN_F 256
#define OUT_F 128
#define NBUCK 391          // coarse buckets of 256 dst-nodes
#define NPART 256          // edge partitions
#define CHUNK (N_EDGES / NPART)   // 6250
#define BCAP 5632          // max edges staged per bucket in fillB (avg 4092, +24 sigma)

typedef __attribute__((ext_vector_type(8))) short short8;
typedef __attribute__((ext_vector_type(4))) float f32x4;

__device__ __forceinline__ unsigned bf16_rne(float f) {
    unsigned u = __float_as_uint(f);
    return (u + 0x7fffu + ((u >> 16) & 1u)) >> 16;
}

// ---------------- masked weight -> transposed bf16  wmT[n][k] ----------------
__global__ void mask_w_kernel(const float* __restrict__ weight,
                              const float* __restrict__ mask_real,
                              unsigned short* __restrict__ wmT) {
    int i = blockIdx.x * blockDim.x + threadIdx.x;
    if (i < IN_F * OUT_F) {
        int k = i >> 7;        // 0..255
        int n = i & 127;       // 0..127
        float v = (mask_real[i] > 0.5f) ? weight[i] : 0.0f;
        wmT[(size_t)n * IN_F + k] = (unsigned short)bf16_rne(v);
    }
}

// ---------------- out-degree (for GEMM row scaling) ----------------
__global__ void outdeg_kernel(const int* __restrict__ src, unsigned* __restrict__ outdeg) {
    int e = blockIdx.x * blockDim.x + threadIdx.x;
    if (e < N_EDGES) atomicAdd(&outdeg[src[e]], 1u);
}

// ---------------- pass 1: per-partition bucket histogram (LDS) ----------------
__global__ __launch_bounds__(256) void hist_kernel(const int* __restrict__ dst,
                                                   unsigned* __restrict__ hist) {
    __shared__ unsigned h[NBUCK];
    int p = blockIdx.x, t = threadIdx.x;
    for (int b = t; b < NBUCK; b += 256) h[b] = 0u;
    __syncthreads();
    int base = p * CHUNK;
    for (int i = t; i < CHUNK; i += 256)
        atomicAdd(&h[(unsigned)dst[base + i] >> 8], 1u);
    __syncthreads();
    for (int b = t; b < NBUCK; b += 256)
        hist[(size_t)p * NBUCK + b] = h[b];
}

// ---------------- scan of hist in (bucket, partition) order ----------------
__global__ __launch_bounds__(256) void scan_reduce_hist(const unsigned* __restrict__ hist,
                                                        unsigned* __restrict__ bsum) {
    __shared__ unsigned red[256];
    int b = blockIdx.x, t = threadIdx.x;
    red[t] = hist[(size_t)t * NBUCK + b];
    __syncthreads();
#pragma unroll
    for (int d = 128; d > 0; d >>= 1) {
        if (t < d) red[t] += red[t + d];
        __syncthreads();
    }
    if (t == 0) bsum[b] = red[0];
}

__global__ __launch_bounds__(512) void scan_spine(const unsigned* __restrict__ bsum,
                                                  unsigned* __restrict__ bpref) {
    __shared__ unsigned part[512];
    int t = threadIdx.x;
    unsigned v = (t < NBUCK) ? bsum[t] : 0u;
    part[t] = v;
    __syncthreads();
#pragma unroll
    for (int d = 1; d < 512; d <<= 1) {
        unsigned x = (t >= d) ? part[t - d] : 0u;
        __syncthreads();
        part[t] += x;
        __syncthreads();
    }
    if (t < NBUCK) bpref[t] = part[t] - v;
}

__global__ __launch_bounds__(256) void scan_apply_hist(const unsigned* __restrict__ hist,
                                                       const unsigned* __restrict__ bpref,
                                                       unsigned* __restrict__ scanned) {
    __shared__ unsigned part[256];
    int b = blockIdx.x, t = threadIdx.x;
    unsigned v = hist[(size_t)t * NBUCK + b];
    part[t] = v;
    __syncthreads();
#pragma unroll
    for (int d = 1; d < 256; d <<= 1) {
        unsigned x = (t >= d) ? part[t - d] : 0u;
        __syncthreads();
        part[t] += x;
        __syncthreads();
    }
    scanned[(size_t)b * 256 + t] = bpref[b] + part[t] - v;
}

// ---------------- pass 2: scatter edges to bucket-major tmp (private ranges) ----------------
__global__ __launch_bounds__(256) void scatter_kernel(const int* __restrict__ src,
                                                      const int* __restrict__ dst,
                                                      const float* __restrict__ ew,
                                                      const unsigned* __restrict__ scanned,
                                                      uint2* __restrict__ tmp) {
    __shared__ unsigned cur[NBUCK];
    int p = blockIdx.x, t = threadIdx.x;
    for (int b = t; b < NBUCK; b += 256) cur[b] = scanned[(size_t)b * 256 + p];
    __syncthreads();
    int base = p * CHUNK;
    for (int i = t; i < CHUNK; i += 256) {
        int e = base + i;
        int s = src[e];
        int d = dst[e];
        unsigned pos = atomicAdd(&cur[(unsigned)d >> 8], 1u);
        tmp[pos] = make_uint2((unsigned)s | (((unsigned)d & 255u) << 17),
                              __float_as_uint(ew[e]));
    }
}

// ---------------- fillB: bucket -> per-node CSR + offsets (all in LDS) ----------------
__global__ __launch_bounds__(256) void fillB_kernel(const uint2* __restrict__ tmp,
                                                    const unsigned* __restrict__ scanned,
                                                    unsigned* __restrict__ offsets,
                                                    uint2* __restrict__ smeta) {
    __shared__ uint2 ebuf[BCAP];        // 44 KB
    __shared__ unsigned hcnt[256];
    __shared__ unsigned pref[256];
    int b = blockIdx.x, t = threadIdx.x;
    unsigned base = scanned[(size_t)b * 256];
    unsigned next = (b == NBUCK - 1) ? (unsigned)N_EDGES : scanned[(size_t)(b + 1) * 256];
    int cnt = (int)(next - base);
    if (cnt > BCAP) cnt = BCAP;
    hcnt[t] = 0u;
    for (int i = t; i < cnt; i += 256) ebuf[i] = tmp[base + i];
    __syncthreads();
    for (int i = t; i < cnt; i += 256) atomicAdd(&hcnt[ebuf[i].x >> 17], 1u);
    __syncthreads();
    unsigned v = hcnt[t];
    pref[t] = v;
    __syncthreads();
#pragma unroll
    for (int d = 1; d < 256; d <<= 1) {
        unsigned x = (t >= d) ? pref[t - d] : 0u;
        __syncthreads();
        pref[t] += x;
        __syncthreads();
    }
    unsigned excl = pref[t] - v;
    int node = b * 256 + t;
    if (node <= N_NODES) offsets[node] = base + excl;
    hcnt[t] = base + excl;
    __syncthreads();
    for (int i = t; i < cnt; i += 256) {
        uint2 m = ebuf[i];
        unsigned pos = atomicAdd(&hcnt[m.x >> 17], 1u);
        smeta[pos] = make_uint2(m.x & 0x1FFFFu, m.y);
    }
}

// ---------------- MFMA bf16 GEMM:  h = (feat @ wm) * outdeg^-0.5, bf16 out ----------------
// block = 64 rows x 128 cols, 4 waves; wave = 16 rows x 128 cols via 8x mfma 16x16x32.
__global__ __launch_bounds__(256) void gemm_kernel(const float* __restrict__ feat,
                                                   const unsigned short* __restrict__ wmT,
                                                   const unsigned* __restrict__ outdeg,
                                                   unsigned short* __restrict__ hb) {
    __shared__ unsigned short sA[64][32];   // 4 KB, row-major [m][k], bf16
    __shared__ unsigned short sB[128][40];  // 10 KB, [n][k] bf16, k padded 32->40
    int t = threadIdx.x;
    int row0 = blockIdx.x * 64;
    int lane = t & 63, wv = t >> 6;
    int m16 = lane & 15, quad = lane >> 4;

    f32x4 acc[8];
#pragma unroll
    for (int i = 0; i < 8; i++) acc[i] = (f32x4){0.f, 0.f, 0.f, 0.f};

    // staging assignments
    int ar = t >> 2;            // A row 0..63
    int ac = (t & 3) * 8;       // A col group
    int arow = min(row0 + ar, N_NODES - 1);
    const float* fptr = feat + (size_t)arow * IN_F + ac;
    int bn = t >> 2;            // B rows bn and bn+64
    int bs = (t & 3) * 8;

    for (int k0 = 0; k0 < IN_F; k0 += 32) {
        // prefetch global before the barrier
        float4 v0 = *(const float4*)(fptr + k0);
        float4 v1 = *(const float4*)(fptr + k0 + 4);
        uint4 bw0 = *(const uint4*)&wmT[(size_t)bn * IN_F + k0 + bs];
        uint4 bw1 = *(const uint4*)&wmT[(size_t)(bn + 64) * IN_F + k0 + bs];
        uint4 pk;
        pk.x = bf16_rne(v0.x) | (bf16_rne(v0.y) << 16);
        pk.y = bf16_rne(v0.z) | (bf16_rne(v0.w) << 16);
        pk.z = bf16_rne(v1.x) | (bf16_rne(v1.y) << 16);
        pk.w = bf16_rne(v1.z) | (bf16_rne(v1.w) << 16);
        __syncthreads();   // previous iteration's LDS reads done
        *(uint4*)&sA[ar][ac] = pk;
        *(uint4*)&sB[bn][bs] = bw0;
        *(uint4*)&sB[bn + 64][bs] = bw1;
        __syncthreads();
        short8 a = *(const short8*)&sA[wv * 16 + m16][quad * 8];
#pragma unroll
        for (int nt = 0; nt < 8; nt++) {
            short8 b = *(const short8*)&sB[nt * 16 + m16][quad * 8];
            acc[nt] = __builtin_amdgcn_mfma_f32_16x16x32_bf16(a, b, acc[nt], 0, 0, 0);
        }
    }
    // epilogue: C[row=quad*4+reg][col=m16] per nt; scale by outdeg^-0.5, store bf16
#pragma unroll
    for (int reg = 0; reg < 4; reg++) {
        int row = row0 + wv * 16 + quad * 4 + reg;
        if (row < N_NODES) {
            float s = rsqrtf(fmaxf((float)outdeg[row], 1.0f));
#pragma unroll
            for (int nt = 0; nt < 8; nt++)
                hb[(size_t)row * OUT_F + nt * 16 + m16] =
                    (unsigned short)bf16_rne(acc[nt][reg] * s);
        }
    }
}

// ---------------- gather: one wave per dst node ----------------
__global__ __launch_bounds__(256) void gather_kernel(const uint2* __restrict__ smeta,
                                                     const unsigned* __restrict__ offsets,
                                                     const unsigned* __restrict__ hrows,
                                                     const float* __restrict__ bias,
                                                     float* __restrict__ out) {
    int lane = threadIdx.x & 63;
    int n = blockIdx.x * 4 + (threadIdx.x >> 6);
    unsigned beg = offsets[n], end = offsets[n + 1];
    int deg = (int)(end - beg);
    float acc0 = 0.0f, acc1 = 0.0f;
    for (int base = 0; base < deg; base += 64) {
        int c = min(64, deg - base);
        unsigned sv = 0;
        float wv = 0.0f;
        if (lane < c) {
            uint2 m = smeta[beg + base + lane];
            sv = m.x;
            wv = __uint_as_float(m.y);
        }
#pragma unroll 4
        for (int i = 0; i < c; i++) {
            unsigned s = __shfl(sv, i);
            float w = __shfl(wv, i);
            unsigned hv = hrows[(size_t)s * (OUT_F / 2) + lane];
            float lo = __uint_as_float(hv << 16);
            float hi = __uint_as_float(hv & 0xffff0000u);
            acc0 = fmaf(lo, w, acc0);
            acc1 = fmaf(hi, w, acc1);
        }
    }
    float s = rsqrtf(fmaxf((float)deg, 1.0f));
    float2 b = *(const float2*)&bias[2 * lane];
    float2 o = make_float2(acc0 * s + b.x, acc1 * s + b.y);
    *(float2*)&out[(size_t)n * OUT_F + 2 * lane] = o;
}

extern "C" void kernel_launch(void* const* d_in, const int* in_sizes, int n_in,
                              void* d_out, int out_size, void* d_ws, size_t ws_size,
                              hipStream_t stream) {
    const float* feat      = (const float*)d_in[0];
    const int*   src       = (const int*)d_in[1];
    const int*   dst       = (const int*)d_in[2];
    const float* ew        = (const float*)d_in[3];
    const float* weight    = (const float*)d_in[4];
    const float* bias      = (const float*)d_in[5];
    const float* mask_real = (const float*)d_in[6];
    float* out = (float*)d_out;

    char* ws = (char*)d_ws;
    size_t o = 0;
    auto take = [&](size_t bytes) {
        char* p = ws + o;
        o = (o + bytes + 255) & ~(size_t)255;
        return p;
    };
    unsigned short* wmT     = (unsigned short*)take((size_t)IN_F * OUT_F * 2);
    unsigned*       outdeg  = (unsigned*)take((size_t)N_NODES * 4);
    unsigned*       offs    = (unsigned*)take((size_t)(N_NODES + 1) * 4);
    unsigned*       hist    = (unsigned*)take((size_t)NPART * NBUCK * 4);
    unsigned*       scanned = (unsigned*)take((size_t)NBUCK * 256 * 4);
    unsigned*       bsum    = (unsigned*)take((size_t)NBUCK * 4);
    unsigned*       bpref   = (unsigned*)take((size_t)NBUCK * 4);
    uint2*          tmp     = (uint2*)take((size_t)N_EDGES * 8);
    uint2*          smeta   = (uint2*)take((size_t)N_EDGES * 8);
    unsigned short* hrows   = (unsigned short*)take((size_t)N_NODES * OUT_F * 2);

    hipMemsetAsync(outdeg, 0, (size_t)N_NODES * 4, stream);

    mask_w_kernel<<<(IN_F * OUT_F + 255) / 256, 256, 0, stream>>>(weight, mask_real, wmT);
    outdeg_kernel<<<(N_EDGES + 255) / 256, 256, 0, stream>>>(src, outdeg);
    hist_kernel<<<NPART, 256, 0, stream>>>(dst, hist);
    scan_reduce_hist<<<NBUCK, 256, 0, stream>>>(hist, bsum);
    scan_spine<<<1, 512, 0, stream>>>(bsum, bpref);
    scan_apply_hist<<<NBUCK, 256, 0, stream>>>(hist, bpref, scanned);
    scatter_kernel<<<NPART, 256, 0, stream>>>(src, dst, ew, scanned, tmp);
    gemm_kernel<<<(N_NODES + 63) / 64, 256, 0, stream>>>(feat, wmT, outdeg, hrows);
    fillB_kernel<<<NBUCK, 256, 0, stream>>>(tmp, scanned, offs, smeta);
    gather_kernel<<<N_NODES / 4, 256, 0, stream>>>(smeta, offs,
                                                   (const unsigned*)hrows, bias, out);
}